// Round 6
// baseline (95.796 us; speedup 1.0000x reference)
//
#include <hip/hip_runtime.h>
#include <math.h>

typedef __attribute__((ext_vector_type(8))) _Float16 f16x8;
typedef __attribute__((ext_vector_type(4))) float f32x4;

#define NPIX 4096
#define C_DIM 128
// 1/sqrt(128) * log2(e): scores arrive in log2-space -> exp2 (v_exp_f32 native)
#define SCALE2 0.12752064638518208f

#if __has_builtin(__builtin_amdgcn_exp2f)
#define EXP2(x) __builtin_amdgcn_exp2f(x)
#else
#define EXP2(x) exp2f(x)
#endif

// ws: fp16 Y panel [b][k][c], rows of 256B, granule-XOR swizzled. 4 MB.
// (Harness poisons the workspace every iteration regardless of use — r0 vs r1
//  measurement — so the panel is free; only kernel time matters.)
#define WS_NEED ((size_t)4 << 20)

// ---------------- conv: y fp32 [c][k] -> fp16 panel [k][c], XCD-matched (validated) ----------------
__global__ __launch_bounds__(256) void conv_y(const float* __restrict__ y,
                                              char* __restrict__ ws)
{
    __shared__ float T[32][132];
    const int wg  = blockIdx.x;
    const int xcd = wg & 7;
    const int b   = xcd >> 1;
    const int sl  = ((xcd & 1) << 6) | (wg >> 3);
    const int k0  = sl * 32;
    const int t   = threadIdx.x;

    {   // read 128c x 32k, coalesced
        const int c = t >> 1, half = t & 1;
        const float* srow = y + ((size_t)b * C_DIM + c) * NPIX + k0 + half * 16;
        float4 rv[4];
        #pragma unroll
        for (int u = 0; u < 4; ++u) rv[u] = *(const float4*)(srow + u * 4);
        #pragma unroll
        for (int u = 0; u < 4; ++u) {
            T[half * 16 + u * 4 + 0][c] = rv[u].x;
            T[half * 16 + u * 4 + 1][c] = rv[u].y;
            T[half * 16 + u * 4 + 2][c] = rv[u].z;
            T[half * 16 + u * 4 + 3][c] = rv[u].w;
        }
    }
    __syncthreads();

    char* panel = ws + (size_t)b * (NPIX * 256);
    const int k = t >> 3, g2 = t & 7;
    f16x8 v0, v1;
    #pragma unroll
    for (int m = 0; m < 8; ++m) {
        v0[m] = (_Float16)T[k][g2 * 16 + m];
        v1[m] = (_Float16)T[k][g2 * 16 + 8 + m];
    }
    const int key = k0 + k, s = key & 7;           // granule-XOR swizzle per key row
    char* drow = panel + (size_t)key * 256;
    *(f16x8*)(drow + (((2 * g2)     ^ s) << 4)) = v0;
    *(f16x8*)(drow + (((2 * g2 + 1) ^ s) << 4)) = v1;
}

// ---------------- main: 512 blocks x 512 thr (2 blocks/CU -> 4 waves/SIMD), 32 q/block ----------------
// r3 post-mortem: the register-double-buffered A-path needs ~135 live VGPRs vs the
// 128 cap of (512,4) -> hot-loop spill ate the occupancy win (uv_main stayed ~42us).
// Fix: Y tiles in wave-private LDS (r0-validated structure: global_load_lds staging,
// granule-XOR ds_read, counted vmcnt, ZERO in-loop barriers), so A-frags are transient
// ds_read results and live VGPRs drop to ~90 -> no spill possible at 4 waves/SIMD.
// 2-buffer x 32KB + 3KB reduce = 67KB <= 80KB/block -> 2 blocks/CU.
__global__ __launch_bounds__(512, 4) void uv_main(const char* __restrict__ ws,
                                                  const float* __restrict__ x,
                                                  float* __restrict__ out)
{
    __shared__ __align__(16) char Ys[2][32768];    // double buffer: 128 keys x 256B fp16
    __shared__ float red[8][32][3];                // cross-wave reduce scratch (3 KB)

    const int t = threadIdx.x, w = t >> 6, l = t & 63;
    const int n16 = l & 15, quad = l >> 4;
    const int wg  = blockIdx.x;
    const int xcd = wg & 7;
    const int b   = xcd >> 1;                      // 2 XCDs per batch: 1MB panel L2-resident
    const int qt  = ((xcd & 1) << 6) | (wg >> 3);  // 0..127
    const int q0  = qt * 32;

    const char* panel = ws + (size_t)b * (NPIX * 256);

    // staging: wave w copies its own rows [w*16, w*16+16): 4 x (64 lanes x 16B)
    int soff[4];
    #pragma unroll
    for (int i = 0; i < 4; ++i) soff[i] = (w * 16 + i * 4) * 256 + l * 16;

    // issue tile 0 stage immediately: its latency hides under the X prologue
    #pragma unroll
    for (int i = 0; i < 4; ++i)
        __builtin_amdgcn_global_load_lds(
            (const __attribute__((address_space(1))) void*)(panel + soff[i]),
            (__attribute__((address_space(3))) void*)(&Ys[0][soff[i]]), 16, 0, 0);

    // ---- one-time: X B-fragments fp16 (SCALE2 folded: scores in log2-space). 32 VGPRs. ----
    f16x8 bx[4][2];                                // [cc][qg]
    {
        const float* xq = x + (size_t)b * C_DIM * NPIX + q0 + n16;
        #pragma unroll
        for (int cc = 0; cc < 4; ++cc)
            #pragma unroll
            for (int qg = 0; qg < 2; ++qg) {
                f16x8 hh;
                #pragma unroll
                for (int j = 0; j < 8; ++j)
                    hh[j] = (_Float16)(xq[(size_t)(cc * 32 + quad * 8 + j) * NPIX + qg * 16] * SCALE2);
                bx[cc][qg] = hh;
            }
    }

    // A-frag LDS read offsets (wave-private rows): row = w*16 + n16, swizzle s = n16&7
    const int arow = w * 16 + n16;
    int aoff[4];
    #pragma unroll
    for (int cc = 0; cc < 4; ++cc)
        aoff[cc] = arow * 256 + (((cc * 4 + quad) ^ (n16 & 7)) << 4);

    // D rows: tile-local key = w*16 + quad*4 + r  (tile = 128 keys = 2 grid rows)
    float gxv[4];
    #pragma unroll
    for (int r = 0; r < 4; ++r) gxv[r] = (float)((w & 3) * 16 + quad * 4 + r) + 0.5f;
    const float gyw = (float)(w >> 2) + 0.5f;      // gy = 2*kt + gyw
    float den[2] = {0.f, 0.f}, nu[2] = {0.f, 0.f}, nv[2] = {0.f, 0.f};

    #pragma unroll 1
    for (int kt = 0; kt < 32; ++kt) {
        char* cur = Ys[kt & 1];

        if (kt < 31) {   // issue tile kt+1, then drain ONLY tile kt (vmcnt(4): kt+1 in flight)
            const char* gt = panel + (size_t)(kt + 1) * 32768;
            char* nb = Ys[(kt + 1) & 1];
            #pragma unroll
            for (int i = 0; i < 4; ++i)
                __builtin_amdgcn_global_load_lds(
                    (const __attribute__((address_space(1))) void*)(gt + soff[i]),
                    (__attribute__((address_space(3))) void*)(&nb[soff[i]]), 16, 0, 0);
            __builtin_amdgcn_s_waitcnt(0x0F74);    // vmcnt(4)
        } else {
            __builtin_amdgcn_s_waitcnt(0x0F70);    // tail: vmcnt(0)
        }

        f32x4 acc[2];
        #pragma unroll
        for (int qg = 0; qg < 2; ++qg) acc[qg] = (f32x4){0.f, 0.f, 0.f, 0.f};

        #pragma unroll
        for (int cc = 0; cc < 4; ++cc) {
            const f16x8 A = *(const f16x8*)(cur + aoff[cc]);
            #pragma unroll
            for (int qg = 0; qg < 2; ++qg)
                acc[qg] = __builtin_amdgcn_mfma_f32_16x16x32_f16(A, bx[cc][qg], acc[qg], 0, 0, 0);
        }

        // softmax accumulation in log2-space: p = 2^s (v_exp_f32 native)
        const float gy = 2.0f * (float)kt + gyw;
        #pragma unroll
        for (int qg = 0; qg < 2; ++qg) {
            float ps = 0.f, pc = 0.f;
            #pragma unroll
            for (int r = 0; r < 4; ++r) {
                const float p = EXP2(acc[qg][r]);
                ps += p;
                pc += p * gxv[r];
            }
            den[qg] += ps;
            nu[qg]  += pc;
            nv[qg]  += gy * ps;
        }
    }

    // ---- reduce across quads (keys within wave), then across 8 waves via LDS ----
    #pragma unroll
    for (int qg = 0; qg < 2; ++qg) {
        #pragma unroll
        for (int mk = 16; mk <= 32; mk <<= 1) {
            den[qg] += __shfl_xor(den[qg], mk);
            nu[qg]  += __shfl_xor(nu[qg],  mk);
            nv[qg]  += __shfl_xor(nv[qg],  mk);
        }
    }
    if (quad == 0) {
        #pragma unroll
        for (int qg = 0; qg < 2; ++qg) {
            red[w][qg * 16 + n16][0] = den[qg];
            red[w][qg * 16 + n16][1] = nu[qg];
            red[w][qg * 16 + n16][2] = nv[qg];
        }
    }
    __syncthreads();
    if (t < 32) {
        float d = 0.f, u = 0.f, v = 0.f;
        #pragma unroll
        for (int ww = 0; ww < 8; ++ww) {
            d += red[ww][t][0];
            u += red[ww][t][1];
            v += red[ww][t][2];
        }
        const float inv = 1.0f / d;
        *(float2*)(out + ((size_t)b * NPIX + q0 + t) * 2) =
            make_float2(u * inv * 0.03125f - 1.0f, v * inv * 0.03125f - 1.0f);
    }
}

// ---------------- fallback (fp32 vector kernel, known-correct) if ws too small ----------------
__global__ __launch_bounds__(256, 2) void uv_attn_kernel(
    const float* __restrict__ x, const float* __restrict__ y, float* __restrict__ out)
{
    __shared__ float Xs[C_DIM][32];
    __shared__ float Ysf[64][128];
    const float SCALE = 0.08838834764831845f;
    const int tid = threadIdx.x;
    const int wgid = blockIdx.x;
    const int xcd = wgid & 7;
    const int b = xcd & 3;
    const int q0 = (((xcd >> 2) << 6) | (wgid >> 3)) * 32;
    const float* xb = x + (size_t)b * C_DIM * NPIX + q0;
    {
        const int cr = tid >> 3;
        const int cc = (tid & 7) << 2;
        #pragma unroll
        for (int i = 0; i < 4; ++i) {
            float4 v = *(const float4*)(xb + (size_t)(cr + (i << 5)) * NPIX + cc);
            v.x *= SCALE; v.y *= SCALE; v.z *= SCALE; v.w *= SCALE;
            *(float4*)(&Xs[cr + (i << 5)][cc]) = v;
        }
    }
    const int rg = tid >> 4;
    const int lane16 = tid & 15;
    const int r0 = rg << 1;
    const int col0 = lane16 << 3;
    float gxv[8];
    #pragma unroll
    for (int j2 = 0; j2 < 8; ++j2) gxv[j2] = (float)((col0 & 63) + j2) + 0.5f;
    const float gyb = (float)(lane16 >> 3) + 0.5f;
    float m_run[2] = {-INFINITY, -INFINITY};
    float den[2] = {0.f, 0.f}, nu[2] = {0.f, 0.f}, nv[2] = {0.f, 0.f};
    const int yr = tid >> 5;
    const int yc = (tid & 31) << 2;
    const float* ybase = y + (size_t)b * C_DIM * NPIX;
    for (int kt = 0; kt < 32; ++kt) {
        float S[2][8];
        #pragma unroll
        for (int r = 0; r < 2; ++r)
            #pragma unroll
            for (int j2 = 0; j2 < 8; ++j2) S[r][j2] = 0.f;
        #pragma unroll
        for (int cb = 0; cb < 2; ++cb) {
            __syncthreads();
            const float* yt = ybase + (size_t)(cb << 6) * NPIX + kt * 128;
            #pragma unroll
            for (int i = 0; i < 8; ++i)
                *(float4*)(&Ysf[yr + (i << 3)][yc]) =
                    *(const float4*)(yt + (size_t)(yr + (i << 3)) * NPIX + yc);
            __syncthreads();
            const int cbase = cb << 6;
            #pragma unroll 16
            for (int c = 0; c < 64; ++c) {
                const float2 xa = *(const float2*)(&Xs[cbase + c][r0]);
                const float4 ya = *(const float4*)(&Ysf[c][col0]);
                const float4 yb4 = *(const float4*)(&Ysf[c][col0 + 4]);
                S[0][0] += xa.x * ya.x;  S[0][1] += xa.x * ya.y;
                S[0][2] += xa.x * ya.z;  S[0][3] += xa.x * ya.w;
                S[0][4] += xa.x * yb4.x; S[0][5] += xa.x * yb4.y;
                S[0][6] += xa.x * yb4.z; S[0][7] += xa.x * yb4.w;
                S[1][0] += xa.y * ya.x;  S[1][1] += xa.y * ya.y;
                S[1][2] += xa.y * ya.z;  S[1][3] += xa.y * ya.w;
                S[1][4] += xa.y * yb4.x; S[1][5] += xa.y * yb4.y;
                S[1][6] += xa.y * yb4.z; S[1][7] += xa.y * yb4.w;
            }
        }
        const float gy = gyb + 2.0f * (float)kt;
        #pragma unroll
        for (int r = 0; r < 2; ++r) {
            float tmax = S[r][0];
            #pragma unroll
            for (int j2 = 1; j2 < 8; ++j2) tmax = fmaxf(tmax, S[r][j2]);
            #pragma unroll
            for (int mk = 8; mk >= 1; mk >>= 1) tmax = fmaxf(tmax, __shfl_xor(tmax, mk, 16));
            const float mnew = fmaxf(m_run[r], tmax);
            const float alpha = __expf(m_run[r] - mnew);
            m_run[r] = mnew;
            float psum = 0.f, pu = 0.f;
            #pragma unroll
            for (int j2 = 0; j2 < 8; ++j2) {
                const float p = __expf(S[r][j2] - mnew);
                psum += p; pu += p * gxv[j2];
            }
            den[r] = den[r] * alpha + psum;
            nu[r] = nu[r] * alpha + pu;
            nv[r] = nv[r] * alpha + gy * psum;
        }
    }
    #pragma unroll
    for (int r = 0; r < 2; ++r)
        #pragma unroll
        for (int mk = 8; mk >= 1; mk >>= 1) {
            den[r] += __shfl_xor(den[r], mk, 16);
            nu[r] += __shfl_xor(nu[r], mk, 16);
            nv[r] += __shfl_xor(nv[r], mk, 16);
        }
    if (lane16 == 0) {
        #pragma unroll
        for (int r = 0; r < 2; ++r) {
            const float inv = 1.0f / den[r];
            const int q = q0 + r0 + r;
            *(float2*)(out + ((size_t)b * NPIX + q) * 2) =
                make_float2(nu[r] * inv * 0.03125f - 1.0f, nv[r] * inv * 0.03125f - 1.0f);
        }
    }
}

extern "C" void kernel_launch(void* const* d_in, const int* in_sizes, int n_in,
                              void* d_out, int out_size, void* d_ws, size_t ws_size,
                              hipStream_t stream) {
    const float* x = (const float*)d_in[0];
    const float* y = (const float*)d_in[1];
    float* out = (float*)d_out;
    if (ws_size >= WS_NEED) {
        hipLaunchKernelGGL(conv_y, dim3(512), dim3(256), 0, stream, y, (char*)d_ws);
        hipLaunchKernelGGL(uv_main, dim3(512), dim3(512), 0, stream,
                           (const char*)d_ws, x, out);
    } else {
        hipLaunchKernelGGL(uv_attn_kernel, dim3(512), dim3(256), 0, stream, x, y, out);
    }
}

// Round 7
// 93.108 us; speedup vs baseline: 1.0289x; 1.0289x over previous
//
#include <hip/hip_runtime.h>
#include <math.h>

typedef __attribute__((ext_vector_type(8))) _Float16 f16x8;
typedef __attribute__((ext_vector_type(4))) float f32x4;

#define NPIX 4096
#define C_DIM 128
// 1/sqrt(128) * log2(e): scores arrive in log2-space -> exp2 (v_exp_f32 native)
#define SCALE2 0.12752064638518208f

#if __has_builtin(__builtin_amdgcn_exp2f)
#define EXP2(x) __builtin_amdgcn_exp2f(x)
#else
#define EXP2(x) exp2f(x)
#endif

// ws: fp16 Y panel [b][k][c], rows of 256B, granule-XOR swizzled. 4 MB.
#define WS_NEED ((size_t)4 << 20)

// ---------------- conv: y fp32 [c][k] -> fp16 panel [k][c], XCD-matched (validated) ----------------
__global__ __launch_bounds__(256) void conv_y(const float* __restrict__ y,
                                              char* __restrict__ ws)
{
    __shared__ float T[32][132];
    const int wg  = blockIdx.x;
    const int xcd = wg & 7;
    const int b   = xcd >> 1;
    const int sl  = ((xcd & 1) << 6) | (wg >> 3);
    const int k0  = sl * 32;
    const int t   = threadIdx.x;

    {   // read 128c x 32k, coalesced
        const int c = t >> 1, half = t & 1;
        const float* srow = y + ((size_t)b * C_DIM + c) * NPIX + k0 + half * 16;
        float4 rv[4];
        #pragma unroll
        for (int u = 0; u < 4; ++u) rv[u] = *(const float4*)(srow + u * 4);
        #pragma unroll
        for (int u = 0; u < 4; ++u) {
            T[half * 16 + u * 4 + 0][c] = rv[u].x;
            T[half * 16 + u * 4 + 1][c] = rv[u].y;
            T[half * 16 + u * 4 + 2][c] = rv[u].z;
            T[half * 16 + u * 4 + 3][c] = rv[u].w;
        }
    }
    __syncthreads();

    char* panel = ws + (size_t)b * (NPIX * 256);
    const int k = t >> 3, g2 = t & 7;
    f16x8 v0, v1;
    #pragma unroll
    for (int m = 0; m < 8; ++m) {
        v0[m] = (_Float16)T[k][g2 * 16 + m];
        v1[m] = (_Float16)T[k][g2 * 16 + 8 + m];
    }
    const int key = k0 + k, s = key & 7;           // granule-XOR swizzle per key row
    char* drow = panel + (size_t)key * 256;
    *(f16x8*)(drow + (((2 * g2)     ^ s) << 4)) = v0;
    *(f16x8*)(drow + (((2 * g2 + 1) ^ s) << 4)) = v1;
}

// ---------------- main: 256 blocks x 1024 thr (1 block/CU, 16 waves = 4/SIMD), TQ=64 ----------------
// r6 post-mortem: TQ=32 @ 4 waves/SIMD == r0's TQ=64 @ 2 waves/SIMD (~36us): the occupancy
// gain was cancelled by 2x per-CU panel traffic + 2x per-wave iteration count. This config
// takes BOTH: TQ=64 (1 MB/CU staging, minimal) AND 4 waves/SIMD, via 1024-thread blocks.
// VGPR fits the 128 cap by construction (r2/r3 spill post-mortems): A-frags are transient
// ds_read results (no reg double-buffer), MFMA split in two qg-halves so only acc[2] (8 regs)
// is live: bx 64 + acc 8 + accum 12 + addr ~20 ~= 105 < 128.
// 256-key tiles, 16 iterations, wave-private staging rows [w*16,(w+1)*16), double-buffered
// 2x64KB LDS + 12KB reduce = 140KB, zero in-loop barriers, counted vmcnt (never drains the
// in-flight tile).
__global__ __launch_bounds__(1024) void uv_main(const char* __restrict__ ws,
                                                const float* __restrict__ x,
                                                float* __restrict__ out)
{
    __shared__ __align__(16) char Ys[2][65536];    // double buffer: 256 keys x 256B fp16
    __shared__ float red[16][64][3];               // cross-wave reduce scratch (12 KB)

    const int t = threadIdx.x, w = t >> 6, l = t & 63;
    const int n16 = l & 15, quad = l >> 4;
    const int wg  = blockIdx.x;
    const int xcd = wg & 7;
    const int b   = xcd >> 1;                      // 2 XCDs per batch: 1MB panel L2-resident
    const int qt  = ((xcd & 1) << 5) | (wg >> 3);  // 0..63
    const int q0  = qt * 64;

    const char* panel = ws + (size_t)b * (NPIX * 256);

    // staging: wave w copies its own rows [w*16, w*16+16): 4 x (64 lanes x 16B)
    int soff[4];
    #pragma unroll
    for (int i = 0; i < 4; ++i) soff[i] = (w * 16 + i * 4) * 256 + l * 16;

    // issue tile 0 stage immediately: its latency hides under the X prologue
    #pragma unroll
    for (int i = 0; i < 4; ++i)
        __builtin_amdgcn_global_load_lds(
            (const __attribute__((address_space(1))) void*)(panel + soff[i]),
            (__attribute__((address_space(3))) void*)(&Ys[0][soff[i]]), 16, 0, 0);

    // ---- one-time: X B-fragments fp16 (SCALE2 folded: scores in log2-space). 64 VGPRs. ----
    f16x8 bx[4][4];                                // [cc][qg]
    {
        const float* xq = x + (size_t)b * C_DIM * NPIX + q0 + n16;
        #pragma unroll
        for (int cc = 0; cc < 4; ++cc)
            #pragma unroll
            for (int qg = 0; qg < 4; ++qg) {
                f16x8 hh;
                #pragma unroll
                for (int j = 0; j < 8; ++j)
                    hh[j] = (_Float16)(xq[(size_t)(cc * 32 + quad * 8 + j) * NPIX + qg * 16] * SCALE2);
                bx[cc][qg] = hh;
            }
    }

    // A-frag LDS read offsets: row = w*16 + n16 (<256), swizzle s = row&7 = n16&7
    const int arow = w * 16 + n16;
    int aoff[4];
    #pragma unroll
    for (int cc = 0; cc < 4; ++cc)
        aoff[cc] = arow * 256 + (((cc * 4 + quad) ^ (n16 & 7)) << 4);

    // D rows: tile-local key = w*16 + quad*4 + r (tile = 256 keys = 4 grid rows)
    float gxv[4];
    #pragma unroll
    for (int r = 0; r < 4; ++r) gxv[r] = (float)((w & 3) * 16 + quad * 4 + r) + 0.5f;
    const float gyw = (float)(w >> 2) + 0.5f;      // gy = 4*kt + gyw
    float den[4] = {0.f, 0.f, 0.f, 0.f}, nu[4] = {0.f, 0.f, 0.f, 0.f}, nv[4] = {0.f, 0.f, 0.f, 0.f};

    #pragma unroll 1
    for (int kt = 0; kt < 16; ++kt) {
        char* cur = Ys[kt & 1];

        if (kt < 15) {   // issue tile kt+1, then drain ONLY tile kt (vmcnt(4): kt+1 in flight)
            const char* gt = panel + (size_t)(kt + 1) * 65536;
            char* nb = Ys[(kt + 1) & 1];
            #pragma unroll
            for (int i = 0; i < 4; ++i)
                __builtin_amdgcn_global_load_lds(
                    (const __attribute__((address_space(1))) void*)(gt + soff[i]),
                    (__attribute__((address_space(3))) void*)(&nb[soff[i]]), 16, 0, 0);
            __builtin_amdgcn_s_waitcnt(0x0F74);    // vmcnt(4)
        } else {
            __builtin_amdgcn_s_waitcnt(0x0F70);    // tail: vmcnt(0)
        }

        const float gy = 4.0f * (float)kt + gyw;

        // ---- qg-half 0 (qg=0,1): acc[2] live only -> ~105 peak VGPRs ----
        {
            f32x4 acc0 = (f32x4){0.f, 0.f, 0.f, 0.f};
            f32x4 acc1 = (f32x4){0.f, 0.f, 0.f, 0.f};
            #pragma unroll
            for (int cc = 0; cc < 4; ++cc) {
                const f16x8 A = *(const f16x8*)(cur + aoff[cc]);
                acc0 = __builtin_amdgcn_mfma_f32_16x16x32_f16(A, bx[cc][0], acc0, 0, 0, 0);
                acc1 = __builtin_amdgcn_mfma_f32_16x16x32_f16(A, bx[cc][1], acc1, 0, 0, 0);
            }
            float ps0 = 0.f, pc0 = 0.f, ps1 = 0.f, pc1 = 0.f;
            #pragma unroll
            for (int r = 0; r < 4; ++r) {
                const float p0 = EXP2(acc0[r]);
                const float p1 = EXP2(acc1[r]);
                ps0 += p0; pc0 += p0 * gxv[r];
                ps1 += p1; pc1 += p1 * gxv[r];
            }
            den[0] += ps0; nu[0] += pc0; nv[0] += gy * ps0;
            den[1] += ps1; nu[1] += pc1; nv[1] += gy * ps1;
        }
        // ---- qg-half 1 (qg=2,3) ----
        {
            f32x4 acc0 = (f32x4){0.f, 0.f, 0.f, 0.f};
            f32x4 acc1 = (f32x4){0.f, 0.f, 0.f, 0.f};
            #pragma unroll
            for (int cc = 0; cc < 4; ++cc) {
                const f16x8 A = *(const f16x8*)(cur + aoff[cc]);
                acc0 = __builtin_amdgcn_mfma_f32_16x16x32_f16(A, bx[cc][2], acc0, 0, 0, 0);
                acc1 = __builtin_amdgcn_mfma_f32_16x16x32_f16(A, bx[cc][3], acc1, 0, 0, 0);
            }
            float ps0 = 0.f, pc0 = 0.f, ps1 = 0.f, pc1 = 0.f;
            #pragma unroll
            for (int r = 0; r < 4; ++r) {
                const float p0 = EXP2(acc0[r]);
                const float p1 = EXP2(acc1[r]);
                ps0 += p0; pc0 += p0 * gxv[r];
                ps1 += p1; pc1 += p1 * gxv[r];
            }
            den[2] += ps0; nu[2] += pc0; nv[2] += gy * ps0;
            den[3] += ps1; nu[3] += pc1; nv[3] += gy * ps1;
        }
    }

    // ---- reduce across quads (keys within wave), then across 16 waves via LDS ----
    #pragma unroll
    for (int qg = 0; qg < 4; ++qg) {
        #pragma unroll
        for (int mk = 16; mk <= 32; mk <<= 1) {
            den[qg] += __shfl_xor(den[qg], mk);
            nu[qg]  += __shfl_xor(nu[qg],  mk);
            nv[qg]  += __shfl_xor(nv[qg],  mk);
        }
    }
    if (quad == 0) {
        #pragma unroll
        for (int qg = 0; qg < 4; ++qg) {
            red[w][qg * 16 + n16][0] = den[qg];
            red[w][qg * 16 + n16][1] = nu[qg];
            red[w][qg * 16 + n16][2] = nv[qg];
        }
    }
    __syncthreads();
    if (t < 64) {
        float d = 0.f, u = 0.f, v = 0.f;
        #pragma unroll
        for (int ww = 0; ww < 16; ++ww) {
            d += red[ww][t][0];
            u += red[ww][t][1];
            v += red[ww][t][2];
        }
        const float inv = 1.0f / d;
        *(float2*)(out + ((size_t)b * NPIX + q0 + t) * 2) =
            make_float2(u * inv * 0.03125f - 1.0f, v * inv * 0.03125f - 1.0f);
    }
}

// ---------------- fallback (fp32 vector kernel, known-correct) if ws too small ----------------
__global__ __launch_bounds__(256, 2) void uv_attn_kernel(
    const float* __restrict__ x, const float* __restrict__ y, float* __restrict__ out)
{
    __shared__ float Xs[C_DIM][32];
    __shared__ float Ysf[64][128];
    const float SCALE = 0.08838834764831845f;
    const int tid = threadIdx.x;
    const int wgid = blockIdx.x;
    const int xcd = wgid & 7;
    const int b = xcd & 3;
    const int q0 = (((xcd >> 2) << 6) | (wgid >> 3)) * 32;
    const float* xb = x + (size_t)b * C_DIM * NPIX + q0;
    {
        const int cr = tid >> 3;
        const int cc = (tid & 7) << 2;
        #pragma unroll
        for (int i = 0; i < 4; ++i) {
            float4 v = *(const float4*)(xb + (size_t)(cr + (i << 5)) * NPIX + cc);
            v.x *= SCALE; v.y *= SCALE; v.z *= SCALE; v.w *= SCALE;
            *(float4*)(&Xs[cr + (i << 5)][cc]) = v;
        }
    }
    const int rg = tid >> 4;
    const int lane16 = tid & 15;
    const int r0 = rg << 1;
    const int col0 = lane16 << 3;
    float gxv[8];
    #pragma unroll
    for (int j2 = 0; j2 < 8; ++j2) gxv[j2] = (float)((col0 & 63) + j2) + 0.5f;
    const float gyb = (float)(lane16 >> 3) + 0.5f;
    float m_run[2] = {-INFINITY, -INFINITY};
    float den[2] = {0.f, 0.f}, nu[2] = {0.f, 0.f}, nv[2] = {0.f, 0.f};
    const int yr = tid >> 5;
    const int yc = (tid & 31) << 2;
    const float* ybase = y + (size_t)b * C_DIM * NPIX;
    for (int kt = 0; kt < 32; ++kt) {
        float S[2][8];
        #pragma unroll
        for (int r = 0; r < 2; ++r)
            #pragma unroll
            for (int j2 = 0; j2 < 8; ++j2) S[r][j2] = 0.f;
        #pragma unroll
        for (int cb = 0; cb < 2; ++cb) {
            __syncthreads();
            const float* yt = ybase + (size_t)(cb << 6) * NPIX + kt * 128;
            #pragma unroll
            for (int i = 0; i < 8; ++i)
                *(float4*)(&Ysf[yr + (i << 3)][yc]) =
                    *(const float4*)(yt + (size_t)(yr + (i << 3)) * NPIX + yc);
            __syncthreads();
            const int cbase = cb << 6;
            #pragma unroll 16
            for (int c = 0; c < 64; ++c) {
                const float2 xa = *(const float2*)(&Xs[cbase + c][r0]);
                const float4 ya = *(const float4*)(&Ysf[c][col0]);
                const float4 yb4 = *(const float4*)(&Ysf[c][col0 + 4]);
                S[0][0] += xa.x * ya.x;  S[0][1] += xa.x * ya.y;
                S[0][2] += xa.x * ya.z;  S[0][3] += xa.x * ya.w;
                S[0][4] += xa.x * yb4.x; S[0][5] += xa.x * yb4.y;
                S[0][6] += xa.x * yb4.z; S[0][7] += xa.x * yb4.w;
                S[1][0] += xa.y * ya.x;  S[1][1] += xa.y * ya.y;
                S[1][2] += xa.y * ya.z;  S[1][3] += xa.y * ya.w;
                S[1][4] += xa.y * yb4.x; S[1][5] += xa.y * yb4.y;
                S[1][6] += xa.y * yb4.z; S[1][7] += xa.y * yb4.w;
            }
        }
        const float gy = gyb + 2.0f * (float)kt;
        #pragma unroll
        for (int r = 0; r < 2; ++r) {
            float tmax = S[r][0];
            #pragma unroll
            for (int j2 = 1; j2 < 8; ++j2) tmax = fmaxf(tmax, S[r][j2]);
            #pragma unroll
            for (int mk = 8; mk >= 1; mk >>= 1) tmax = fmaxf(tmax, __shfl_xor(tmax, mk, 16));
            const float mnew = fmaxf(m_run[r], tmax);
            const float alpha = __expf(m_run[r] - mnew);
            m_run[r] = mnew;
            float psum = 0.f, pu = 0.f;
            #pragma unroll
            for (int j2 = 0; j2 < 8; ++j2) {
                const float p = __expf(S[r][j2] - mnew);
                psum += p; pu += p * gxv[j2];
            }
            den[r] = den[r] * alpha + psum;
            nu[r] = nu[r] * alpha + pu;
            nv[r] = nv[r] * alpha + gy * psum;
        }
    }
    #pragma unroll
    for (int r = 0; r < 2; ++r)
        #pragma unroll
        for (int mk = 8; mk >= 1; mk >>= 1) {
            den[r] += __shfl_xor(den[r], mk, 16);
            nu[r] += __shfl_xor(nu[r], mk, 16);
            nv[r] += __shfl_xor(nv[r], mk, 16);
        }
    if (lane16 == 0) {
        #pragma unroll
        for (int r = 0; r < 2; ++r) {
            const float inv = 1.0f / den[r];
            const int q = q0 + r0 + r;
            *(float2*)(out + ((size_t)b * NPIX + q) * 2) =
                make_float2(nu[r] * inv * 0.03125f - 1.0f, nv[r] * inv * 0.03125f - 1.0f);
        }
    }
}

extern "C" void kernel_launch(void* const* d_in, const int* in_sizes, int n_in,
                              void* d_out, int out_size, void* d_ws, size_t ws_size,
                              hipStream_t stream) {
    const float* x = (const float*)d_in[0];
    const float* y = (const float*)d_in[1];
    float* out = (float*)d_out;
    if (ws_size >= WS_NEED) {
        hipLaunchKernelGGL(conv_y, dim3(512), dim3(256), 0, stream, y, (char*)d_ws);
        hipLaunchKernelGGL(uv_main, dim3(256), dim3(1024), 0, stream,
                           (const char*)d_ws, x, out);
    } else {
        hipLaunchKernelGGL(uv_attn_kernel, dim3(512), dim3(256), 0, stream, x, y, out);
    }
}